// Round 11
// baseline (176.833 us; speedup 1.0000x reference)
//
#include <hip/hip_runtime.h>
#include <math.h>

#define FT_IN  40960
#define FFT_IN 640
#define FT_OUT 256
#define NA     30
#define NSLICE 4          // 64-col slices (128 B f16 rows); XCD x serves slice x%4
#define BPB    64         // boards per gather block (512 thr = 64 boards x 8 lanes)

typedef _Float16 h2 __attribute__((ext_vector_type(2)));
typedef unsigned u32x4 __attribute__((ext_vector_type(4)));

__device__ __forceinline__ h2 u2h2(unsigned u) {
    union { unsigned u; h2 h; } c; c.u = u; return c.h;
}
__device__ __forceinline__ unsigned pkh(float a, float b) {
    union { h2 h; unsigned u; } c; c.h = h2{(_Float16)a, (_Float16)b}; return c.u;
}

// ---------- fused prep: f32->f16 sliced convert (ft, fft) + index pack ----------
// sliced layout: [NSLICE][nrows][64 f16]; one row-slice = 128 B
__device__ __forceinline__ void conv_block(const float* __restrict__ src,
                                           unsigned* __restrict__ dst,
                                           int nrows, int bid, int tid)
{
    int t = bid * 256 + tid;
    int total = nrows * 32;               // 32 uint4 chunks (8 cols each) per row
    if (t >= total) return;
    int r = t >> 5, g = t & 31;           // chunk g: cols [8g, 8g+8)
    int s = g >> 3, d = g & 7;            // slice (64 cols = 8 chunks), chunk-within-slice
    const float4* sp = (const float4*)(src + (size_t)r * FT_OUT + g * 8);
    float4 v0 = sp[0], v1 = sp[1];
    uint4 u;
    u.x = pkh(v0.x, v0.y); u.y = pkh(v0.z, v0.w);
    u.z = pkh(v1.x, v1.y); u.w = pkh(v1.z, v1.w);
    ((uint4*)dst)[((size_t)s * nrows + r) * 8 + d] = u;
}

__global__ __launch_bounds__(256) void prep(
    const float* __restrict__ ft_w, const float* __restrict__ fft_w,
    const int* __restrict__ stm, const int* __restrict__ nstm,
    const int* __restrict__ fstm, const int* __restrict__ fnstm,
    unsigned* __restrict__ ft_o, unsigned* __restrict__ fft_o,
    ushort4* __restrict__ pidx, int n_boards, int nb_ft, int nb_fft)
{
    int bid = blockIdx.x;
    if (bid < nb_ft) {
        conv_block(ft_w, ft_o, FT_IN, bid, threadIdx.x);
    } else if (bid < nb_ft + nb_fft) {
        conv_block(fft_w, fft_o, FFT_IN, bid - nb_ft, threadIdx.x);
    } else {
        int t = (bid - nb_ft - nb_fft) * 256 + (int)threadIdx.x;
        int total = n_boards * NA;
        if (t < total) {
            int board = t / NA, a = t - board * NA;
            ushort4 v;
            v.x = (unsigned short)stm[t];  v.y = (unsigned short)nstm[t];
            v.z = (unsigned short)fstm[t]; v.w = (unsigned short)fnstm[t];
            pidx[(size_t)a * n_boards + board] = v;   // transposed [a][board]
        }
    }
}

// ---------- gather: all 4 streams as 128 B global row-requests; max TLP ----------
// 512 threads = 64 boards x 8 lanes; lane owns 8 cols (16 B) of the 64-col slice.
// LDS holds only the staged indices (15 KB) -> 4 blocks/CU = 32 waves/CU.
__global__ __launch_bounds__(512, 8) void nnue_gather(
    const uint2* __restrict__ pidx,      // [NA][n_boards] packed ushort4
    const char* __restrict__ ft, const char* __restrict__ fft,
    const float* __restrict__ ft_b, const float* __restrict__ fft_b,
    const float* __restrict__ out_w, float* __restrict__ partial, int n_boards)
{
    __shared__ uint2 lidx[NA * BPB];     // 15360 B
    const int slice = blockIdx.x & (NSLICE - 1);
    const int group = blockIdx.x >> 2;
    const int tid = (int)threadIdx.x;

    for (int i = tid; i < NA * BPB; i += 512) {        // [a][board] rows of 64 uint2
        int b = i & (BPB - 1);
        int bd = group * BPB + b;
        uint2 v; v.x = 0u; v.y = 0u;
        if (bd < n_boards) v = pidx[(size_t)(i >> 6) * n_boards + bd];
        lidx[i] = v;
    }
    __syncthreads();

    const int sub = tid >> 3, ql = tid & 7;
    int board = group * BPB + sub;
    const bool active = board < n_boards;
    const unsigned qlo = (unsigned)(ql << 4);
    const char* ftS  = ft  + (size_t)slice * FT_IN  * 128 + qlo;
    const char* fftS = fft + (size_t)slice * FFT_IN * 128 + qlo;
    const int col = slice * 64 + ql * 8;

    h2 z = h2{(_Float16)0.f, (_Float16)0.f};
    h2 a0[4] = {z, z, z, z};     // stm half
    h2 a1[4] = {z, z, z, z};     // nstm half

    #pragma unroll
    for (int a = 0; a < NA; ++a) {
        uint2 iv = lidx[a * BPB + sub];
        u32x4 u0 = *(const u32x4*)(ftS  + ((iv.x & 0xFFFFu) << 7));
        u32x4 u1 = *(const u32x4*)(ftS  + ((iv.x >> 16) << 7));
        u32x4 g0 = *(const u32x4*)(fftS + ((iv.y & 0xFFFFu) << 7));
        u32x4 g1 = *(const u32x4*)(fftS + ((iv.y >> 16) << 7));
        a0[0] += u2h2(u0.x); a0[1] += u2h2(u0.y); a0[2] += u2h2(u0.z); a0[3] += u2h2(u0.w);
        a1[0] += u2h2(u1.x); a1[1] += u2h2(u1.y); a1[2] += u2h2(u1.z); a1[3] += u2h2(u1.w);
        a0[0] += u2h2(g0.x); a0[1] += u2h2(g0.y); a0[2] += u2h2(g0.z); a0[3] += u2h2(g0.w);
        a1[0] += u2h2(g1.x); a1[1] += u2h2(g1.y); a1[2] += u2h2(g1.z); a1[3] += u2h2(g1.w);
    }

    // epilogue: f32 bias + clip + partial dot
    float h0[8], h1[8];
    #pragma unroll
    for (int i = 0; i < 4; ++i) {
        h0[2*i] = (float)a0[i].x; h0[2*i+1] = (float)a0[i].y;
        h1[2*i] = (float)a1[i].x; h1[2*i+1] = (float)a1[i].y;
    }
    const float4* bfp = (const float4*)(ft_b  + col);
    const float4* bgp = (const float4*)(fft_b + col);
    float4 bf0 = bfp[0], bf1 = bfp[1], bg0 = bgp[0], bg1 = bgp[1];
    float bias[8] = {bf0.x+bg0.x, bf0.y+bg0.y, bf0.z+bg0.z, bf0.w+bg0.w,
                     bf1.x+bg1.x, bf1.y+bg1.y, bf1.z+bg1.z, bf1.w+bg1.w};
    const float4* w0p = (const float4*)(out_w + col);
    const float4* w1p = (const float4*)(out_w + FT_OUT + col);
    float4 w00 = w0p[0], w01 = w0p[1], w10 = w1p[0], w11 = w1p[1];
    float w0[8] = {w00.x, w00.y, w00.z, w00.w, w01.x, w01.y, w01.z, w01.w};
    float w1[8] = {w10.x, w10.y, w10.z, w10.w, w11.x, w11.y, w11.z, w11.w};

    float p = 0.f;
    #pragma unroll
    for (int i = 0; i < 8; ++i) {
        p += fminf(fmaxf(h0[i] + bias[i], 0.f), 1.f) * w0[i];
        p += fminf(fmaxf(h1[i] + bias[i], 0.f), 1.f) * w1[i];
    }
    p += __shfl_xor(p, 1, 64);
    p += __shfl_xor(p, 2, 64);
    p += __shfl_xor(p, 4, 64);
    if (active && ql == 0)
        partial[(size_t)slice * n_boards + board] = p;
}

// ---------- final: sum 4 partials + sigmoid ----------
__global__ __launch_bounds__(256) void nnue_final(
    const float* __restrict__ partial, const float* __restrict__ out_b,
    float* __restrict__ out, int n)
{
    int b = blockIdx.x * blockDim.x + threadIdx.x;
    if (b >= n) return;
    float zv = out_b[0];
    #pragma unroll
    for (int s = 0; s < NSLICE; ++s) zv += partial[(size_t)s * n + b];
    out[b] = 1.0f / (1.0f + expf(-zv));
}

// ---------- fallback: direct f32 gather (if ws too small) ----------
__global__ __launch_bounds__(256) void nnue_fwd_direct(
    const int* __restrict__ stm_idx, const int* __restrict__ nstm_idx,
    const int* __restrict__ f_stm_idx, const int* __restrict__ f_nstm_idx,
    const float* __restrict__ ft_w, const float* __restrict__ ft_b,
    const float* __restrict__ fft_w, const float* __restrict__ fft_b,
    const float* __restrict__ out_w, const float* __restrict__ out_b,
    float* __restrict__ out, int n_boards)
{
    const int board = (int)((blockIdx.x * blockDim.x + threadIdx.x) >> 6);
    const int lane  = (int)(threadIdx.x & 63);
    if (board >= n_boards) return;
    const int col = lane << 2;
    const float4 ftb  = *(const float4*)(ft_b  + col);
    const float4 fftb = *(const float4*)(fft_b + col);
    float a0x = ftb.x + fftb.x, a0y = ftb.y + fftb.y,
          a0z = ftb.z + fftb.z, a0w = ftb.w + fftb.w;
    float a1x = a0x, a1y = a0y, a1z = a0z, a1w = a0w;
    const int* si  = stm_idx    + (size_t)board * NA;
    const int* ni  = nstm_idx   + (size_t)board * NA;
    const int* fsi = f_stm_idx  + (size_t)board * NA;
    const int* fni = f_nstm_idx + (size_t)board * NA;
    #pragma unroll 5
    for (int a = 0; a < NA; ++a) {
        const float4 r0 = *(const float4*)(ft_w  + (size_t)si[a]  * FT_OUT + col);
        const float4 r1 = *(const float4*)(ft_w  + (size_t)ni[a]  * FT_OUT + col);
        const float4 r2 = *(const float4*)(fft_w + (size_t)fsi[a] * FT_OUT + col);
        const float4 r3 = *(const float4*)(fft_w + (size_t)fni[a] * FT_OUT + col);
        a0x += r0.x + r2.x; a0y += r0.y + r2.y; a0z += r0.z + r2.z; a0w += r0.w + r2.w;
        a1x += r1.x + r3.x; a1y += r1.y + r3.y; a1z += r1.z + r3.z; a1w += r1.w + r3.w;
    }
    a0x = fminf(fmaxf(a0x, 0.f), 1.f); a0y = fminf(fmaxf(a0y, 0.f), 1.f);
    a0z = fminf(fmaxf(a0z, 0.f), 1.f); a0w = fminf(fmaxf(a0w, 0.f), 1.f);
    a1x = fminf(fmaxf(a1x, 0.f), 1.f); a1y = fminf(fmaxf(a1y, 0.f), 1.f);
    a1z = fminf(fmaxf(a1z, 0.f), 1.f); a1w = fminf(fmaxf(a1w, 0.f), 1.f);
    const float4 w0 = *(const float4*)(out_w + col);
    const float4 w1 = *(const float4*)(out_w + FT_OUT + col);
    float p = a0x * w0.x + a0y * w0.y + a0z * w0.z + a0w * w0.w
            + a1x * w1.x + a1y * w1.y + a1z * w1.z + a1w * w1.w;
    #pragma unroll
    for (int off = 32; off > 0; off >>= 1) p += __shfl_down(p, off, 64);
    if (lane == 0) out[board] = 1.0f / (1.0f + expf(-(p + out_b[0])));
}

extern "C" void kernel_launch(void* const* d_in, const int* in_sizes, int n_in,
                              void* d_out, int out_size, void* d_ws, size_t ws_size,
                              hipStream_t stream) {
    const int*   stm_idx    = (const int*)d_in[0];
    const int*   nstm_idx   = (const int*)d_in[1];
    const int*   f_stm_idx  = (const int*)d_in[2];
    const int*   f_nstm_idx = (const int*)d_in[3];
    const float* ft_w  = (const float*)d_in[4];
    const float* ft_b  = (const float*)d_in[5];
    const float* fft_w = (const float*)d_in[6];
    const float* fft_b = (const float*)d_in[7];
    const float* out_w = (const float*)d_in[8];
    const float* out_b = (const float*)d_in[9];
    float* out = (float*)d_out;

    const int n_boards = in_sizes[0] / NA;

    const size_t ft_bytes   = (size_t)FT_IN  * FT_OUT * 2;               // 20.97 MB f16
    const size_t fft_bytes  = (size_t)FFT_IN * FT_OUT * 2;               // 320 KB
    const size_t pidx_bytes = (size_t)n_boards * NA * sizeof(ushort4);   // 3.93 MB
    const size_t part_bytes = (size_t)n_boards * NSLICE * sizeof(float); // 256 KB
    const size_t need = ft_bytes + fft_bytes + pidx_bytes + part_bytes;

    if (ws_size < need) {
        const int grid = (n_boards + 3) / 4;
        nnue_fwd_direct<<<grid, 256, 0, stream>>>(stm_idx, nstm_idx, f_stm_idx, f_nstm_idx,
                                                  ft_w, ft_b, fft_w, fft_b, out_w, out_b,
                                                  out, n_boards);
        return;
    }

    char* wsp = (char*)d_ws;
    unsigned* ws_ft   = (unsigned*)wsp;            wsp += ft_bytes;
    unsigned* ws_fft  = (unsigned*)wsp;            wsp += fft_bytes;
    ushort4*  ws_pidx = (ushort4*)wsp;             wsp += pidx_bytes;
    float*    ws_part = (float*)wsp;

    {   // fused prep: converts + index pack in one dispatch
        const int nb_ft   = FT_IN  * 32 / 256;               // 5120
        const int nb_fft  = FFT_IN * 32 / 256;               // 80
        const int nb_pack = (n_boards * NA + 255) / 256;
        prep<<<nb_ft + nb_fft + nb_pack, 256, 0, stream>>>(
            ft_w, fft_w, stm_idx, nstm_idx, f_stm_idx, f_nstm_idx,
            ws_ft, ws_fft, ws_pidx, n_boards, nb_ft, nb_fft);
    }
    {   // sliced gather (128 B row requests, 4 blocks/CU)
        int groups = (n_boards + BPB - 1) / BPB;
        nnue_gather<<<groups * NSLICE, 512, 0, stream>>>(
            (const uint2*)ws_pidx, (const char*)ws_ft, (const char*)ws_fft,
            ft_b, fft_b, out_w, ws_part, n_boards);
    }
    {   // reduce partials + sigmoid
        nnue_final<<<(n_boards + 255) / 256, 256, 0, stream>>>(ws_part, out_b, out, n_boards);
    }
}

// Round 12
// 146.073 us; speedup vs baseline: 1.2106x; 1.2106x over previous
//
#include <hip/hip_runtime.h>
#include <math.h>

#define FT_IN  40960
#define FFT_IN 640
#define FT_OUT 256
#define NA     30
#define NSLICE 4          // 64-col slices (128 B f16 rows); XCD x serves slice x%4
#define BPB    128        // boards per gather block (1024 thr = 128 boards x 8 lanes)

typedef _Float16 h2 __attribute__((ext_vector_type(2)));
typedef unsigned u32x4 __attribute__((ext_vector_type(4)));

__device__ __forceinline__ h2 u2h2(unsigned u) {
    union { unsigned u; h2 h; } c; c.u = u; return c.h;
}
__device__ __forceinline__ unsigned pkh(float a, float b) {
    union { h2 h; unsigned u; } c; c.h = h2{(_Float16)a, (_Float16)b}; return c.u;
}

// ---------- fused prep: f32->f16 sliced convert (ft, fft) + index pack ----------
// sliced layout: [NSLICE][nrows][64 f16]; one row-slice = 128 B
__device__ __forceinline__ void conv_block(const float* __restrict__ src,
                                           unsigned* __restrict__ dst,
                                           int nrows, int bid, int tid)
{
    int t = bid * 256 + tid;
    int total = nrows * 32;               // 32 uint4 chunks (8 cols each) per row
    if (t >= total) return;
    int r = t >> 5, g = t & 31;           // chunk g: cols [8g, 8g+8)
    int s = g >> 3, d = g & 7;            // slice (64 cols = 8 chunks), chunk-within-slice
    const float4* sp = (const float4*)(src + (size_t)r * FT_OUT + g * 8);
    float4 v0 = sp[0], v1 = sp[1];
    uint4 u;
    u.x = pkh(v0.x, v0.y); u.y = pkh(v0.z, v0.w);
    u.z = pkh(v1.x, v1.y); u.w = pkh(v1.z, v1.w);
    ((uint4*)dst)[((size_t)s * nrows + r) * 8 + d] = u;
}

__global__ __launch_bounds__(256) void prep(
    const float* __restrict__ ft_w, const float* __restrict__ fft_w,
    const int* __restrict__ stm, const int* __restrict__ nstm,
    const int* __restrict__ fstm, const int* __restrict__ fnstm,
    unsigned* __restrict__ ft_o, unsigned* __restrict__ fft_o,
    ushort4* __restrict__ pidx, int n_boards, int nb_ft, int nb_fft)
{
    int bid = blockIdx.x;
    if (bid < nb_ft) {
        conv_block(ft_w, ft_o, FT_IN, bid, threadIdx.x);
    } else if (bid < nb_ft + nb_fft) {
        conv_block(fft_w, fft_o, FFT_IN, bid - nb_ft, threadIdx.x);
    } else {
        int t = (bid - nb_ft - nb_fft) * 256 + (int)threadIdx.x;
        int total = n_boards * NA;
        if (t < total) {
            int board = t / NA, a = t - board * NA;
            ushort4 v;
            v.x = (unsigned short)stm[t];  v.y = (unsigned short)nstm[t];
            v.z = (unsigned short)fstm[t]; v.w = (unsigned short)fnstm[t];
            pidx[(size_t)a * n_boards + board] = v;   // transposed [a][board]
        }
    }
}

// ---------- gather: ft 128 B row-requests from L2 slice; fft in 80 KB LDS;
// indices via nontemporal global loads (no L2 pollution). 1024 thr = 128 boards
// x 8 lanes; 2 blocks/CU = 32 waves/CU (LDS 2 x 80 KB = 160 KB exactly).
__global__ __launch_bounds__(1024, 8) void nnue_gather(
    const unsigned long long* __restrict__ pidx,  // [NA][n_boards] packed ushort4
    const char* __restrict__ ft, const char* __restrict__ fft,
    const float* __restrict__ ft_b, const float* __restrict__ fft_b,
    const float* __restrict__ out_w, float* __restrict__ partial, int n_boards)
{
    extern __shared__ u32x4 lfft[];      // [FFT_IN][8] = 81920 B (rows span all 32 banks)
    const int slice = blockIdx.x & (NSLICE - 1);
    const int group = blockIdx.x >> 2;
    const int tid = (int)threadIdx.x;

    {   // stage fft slice
        const u32x4* fsrc = (const u32x4*)(fft + (size_t)slice * FFT_IN * 128);
        for (int i = tid; i < FFT_IN * 8; i += 1024)
            lfft[i] = fsrc[i];
    }
    __syncthreads();

    const int sub = tid >> 3, ql = tid & 7;
    int board = group * BPB + sub;
    const bool active = board < n_boards;
    if (!active) board = n_boards - 1;
    const unsigned qlo = (unsigned)(ql << 4);
    const char* ftS = ft + (size_t)slice * FT_IN * 128 + qlo;
    const int col = slice * 64 + ql * 8;

    h2 z = h2{(_Float16)0.f, (_Float16)0.f};
    h2 a0[4] = {z, z, z, z};     // stm half
    h2 a1[4] = {z, z, z, z};     // nstm half

    const unsigned long long* ip = pidx + board;

    #pragma unroll
    for (int a = 0; a < NA; ++a) {
        unsigned long long iv =
            __builtin_nontemporal_load(ip + (size_t)a * n_boards);
        unsigned lo = (unsigned)iv, hi = (unsigned)(iv >> 32);
        u32x4 u0 = *(const u32x4*)(ftS + ((lo & 0xFFFFu) << 7));
        u32x4 u1 = *(const u32x4*)(ftS + ((lo >> 16) << 7));
        u32x4 g0 = lfft[((hi & 0xFFFFu) << 3) + ql];
        u32x4 g1 = lfft[((hi >> 16) << 3) + ql];
        a0[0] += u2h2(u0.x); a0[1] += u2h2(u0.y); a0[2] += u2h2(u0.z); a0[3] += u2h2(u0.w);
        a1[0] += u2h2(u1.x); a1[1] += u2h2(u1.y); a1[2] += u2h2(u1.z); a1[3] += u2h2(u1.w);
        a0[0] += u2h2(g0.x); a0[1] += u2h2(g0.y); a0[2] += u2h2(g0.z); a0[3] += u2h2(g0.w);
        a1[0] += u2h2(g1.x); a1[1] += u2h2(g1.y); a1[2] += u2h2(g1.z); a1[3] += u2h2(g1.w);
    }

    // epilogue: f32 bias + clip + partial dot
    float h0[8], h1[8];
    #pragma unroll
    for (int i = 0; i < 4; ++i) {
        h0[2*i] = (float)a0[i].x; h0[2*i+1] = (float)a0[i].y;
        h1[2*i] = (float)a1[i].x; h1[2*i+1] = (float)a1[i].y;
    }
    const float4* bfp = (const float4*)(ft_b  + col);
    const float4* bgp = (const float4*)(fft_b + col);
    float4 bf0 = bfp[0], bf1 = bfp[1], bg0 = bgp[0], bg1 = bgp[1];
    float bias[8] = {bf0.x+bg0.x, bf0.y+bg0.y, bf0.z+bg0.z, bf0.w+bg0.w,
                     bf1.x+bg1.x, bf1.y+bg1.y, bf1.z+bg1.z, bf1.w+bg1.w};
    const float4* w0p = (const float4*)(out_w + col);
    const float4* w1p = (const float4*)(out_w + FT_OUT + col);
    float4 w00 = w0p[0], w01 = w0p[1], w10 = w1p[0], w11 = w1p[1];
    float w0[8] = {w00.x, w00.y, w00.z, w00.w, w01.x, w01.y, w01.z, w01.w};
    float w1[8] = {w10.x, w10.y, w10.z, w10.w, w11.x, w11.y, w11.z, w11.w};

    float p = 0.f;
    #pragma unroll
    for (int i = 0; i < 8; ++i) {
        p += fminf(fmaxf(h0[i] + bias[i], 0.f), 1.f) * w0[i];
        p += fminf(fmaxf(h1[i] + bias[i], 0.f), 1.f) * w1[i];
    }
    p += __shfl_xor(p, 1, 64);
    p += __shfl_xor(p, 2, 64);
    p += __shfl_xor(p, 4, 64);
    if (active && ql == 0)
        partial[(size_t)slice * n_boards + board] = p;
}

// ---------- final: sum 4 partials + sigmoid ----------
__global__ __launch_bounds__(256) void nnue_final(
    const float* __restrict__ partial, const float* __restrict__ out_b,
    float* __restrict__ out, int n)
{
    int b = blockIdx.x * blockDim.x + threadIdx.x;
    if (b >= n) return;
    float zv = out_b[0];
    #pragma unroll
    for (int s = 0; s < NSLICE; ++s) zv += partial[(size_t)s * n + b];
    out[b] = 1.0f / (1.0f + expf(-zv));
}

// ---------- fallback: direct f32 gather (if ws too small) ----------
__global__ __launch_bounds__(256) void nnue_fwd_direct(
    const int* __restrict__ stm_idx, const int* __restrict__ nstm_idx,
    const int* __restrict__ f_stm_idx, const int* __restrict__ f_nstm_idx,
    const float* __restrict__ ft_w, const float* __restrict__ ft_b,
    const float* __restrict__ fft_w, const float* __restrict__ fft_b,
    const float* __restrict__ out_w, const float* __restrict__ out_b,
    float* __restrict__ out, int n_boards)
{
    const int board = (int)((blockIdx.x * blockDim.x + threadIdx.x) >> 6);
    const int lane  = (int)(threadIdx.x & 63);
    if (board >= n_boards) return;
    const int col = lane << 2;
    const float4 ftb  = *(const float4*)(ft_b  + col);
    const float4 fftb = *(const float4*)(fft_b + col);
    float a0x = ftb.x + fftb.x, a0y = ftb.y + fftb.y,
          a0z = ftb.z + fftb.z, a0w = ftb.w + fftb.w;
    float a1x = a0x, a1y = a0y, a1z = a0z, a1w = a0w;
    const int* si  = stm_idx    + (size_t)board * NA;
    const int* ni  = nstm_idx   + (size_t)board * NA;
    const int* fsi = f_stm_idx  + (size_t)board * NA;
    const int* fni = f_nstm_idx + (size_t)board * NA;
    #pragma unroll 5
    for (int a = 0; a < NA; ++a) {
        const float4 r0 = *(const float4*)(ft_w  + (size_t)si[a]  * FT_OUT + col);
        const float4 r1 = *(const float4*)(ft_w  + (size_t)ni[a]  * FT_OUT + col);
        const float4 r2 = *(const float4*)(fft_w + (size_t)fsi[a] * FT_OUT + col);
        const float4 r3 = *(const float4*)(fft_w + (size_t)fni[a] * FT_OUT + col);
        a0x += r0.x + r2.x; a0y += r0.y + r2.y; a0z += r0.z + r2.z; a0w += r0.w + r2.w;
        a1x += r1.x + r3.x; a1y += r1.y + r3.y; a1z += r1.z + r3.z; a1w += r1.w + r3.w;
    }
    a0x = fminf(fmaxf(a0x, 0.f), 1.f); a0y = fminf(fmaxf(a0y, 0.f), 1.f);
    a0z = fminf(fmaxf(a0z, 0.f), 1.f); a0w = fminf(fmaxf(a0w, 0.f), 1.f);
    a1x = fminf(fmaxf(a1x, 0.f), 1.f); a1y = fminf(fmaxf(a1y, 0.f), 1.f);
    a1z = fminf(fmaxf(a1z, 0.f), 1.f); a1w = fminf(fmaxf(a1w, 0.f), 1.f);
    const float4 w0 = *(const float4*)(out_w + col);
    const float4 w1 = *(const float4*)(out_w + FT_OUT + col);
    float p = a0x * w0.x + a0y * w0.y + a0z * w0.z + a0w * w0.w
            + a1x * w1.x + a1y * w1.y + a1z * w1.z + a1w * w1.w;
    #pragma unroll
    for (int off = 32; off > 0; off >>= 1) p += __shfl_down(p, off, 64);
    if (lane == 0) out[board] = 1.0f / (1.0f + expf(-(p + out_b[0])));
}

extern "C" void kernel_launch(void* const* d_in, const int* in_sizes, int n_in,
                              void* d_out, int out_size, void* d_ws, size_t ws_size,
                              hipStream_t stream) {
    const int*   stm_idx    = (const int*)d_in[0];
    const int*   nstm_idx   = (const int*)d_in[1];
    const int*   f_stm_idx  = (const int*)d_in[2];
    const int*   f_nstm_idx = (const int*)d_in[3];
    const float* ft_w  = (const float*)d_in[4];
    const float* ft_b  = (const float*)d_in[5];
    const float* fft_w = (const float*)d_in[6];
    const float* fft_b = (const float*)d_in[7];
    const float* out_w = (const float*)d_in[8];
    const float* out_b = (const float*)d_in[9];
    float* out = (float*)d_out;

    const int n_boards = in_sizes[0] / NA;

    const size_t ft_bytes   = (size_t)FT_IN  * FT_OUT * 2;               // 20.97 MB f16
    const size_t fft_bytes  = (size_t)FFT_IN * FT_OUT * 2;               // 320 KB
    const size_t pidx_bytes = (size_t)n_boards * NA * sizeof(ushort4);   // 3.93 MB
    const size_t part_bytes = (size_t)n_boards * NSLICE * sizeof(float); // 256 KB
    const size_t need = ft_bytes + fft_bytes + pidx_bytes + part_bytes;

    const size_t lds_bytes = (size_t)FFT_IN * 128;                        // 81920

    bool ok = (ws_size >= need);
    if (ok) {
        ok = (hipFuncSetAttribute((const void*)nnue_gather,
                                  hipFuncAttributeMaxDynamicSharedMemorySize,
                                  (int)lds_bytes) == hipSuccess);
    }
    if (!ok) {
        const int grid = (n_boards + 3) / 4;
        nnue_fwd_direct<<<grid, 256, 0, stream>>>(stm_idx, nstm_idx, f_stm_idx, f_nstm_idx,
                                                  ft_w, ft_b, fft_w, fft_b, out_w, out_b,
                                                  out, n_boards);
        return;
    }

    char* wsp = (char*)d_ws;
    unsigned* ws_ft   = (unsigned*)wsp;            wsp += ft_bytes;
    unsigned* ws_fft  = (unsigned*)wsp;            wsp += fft_bytes;
    ushort4*  ws_pidx = (ushort4*)wsp;             wsp += pidx_bytes;
    float*    ws_part = (float*)wsp;

    {   // fused prep: converts + index pack in one dispatch
        const int nb_ft   = FT_IN  * 32 / 256;               // 5120
        const int nb_fft  = FFT_IN * 32 / 256;               // 80
        const int nb_pack = (n_boards * NA + 255) / 256;
        prep<<<nb_ft + nb_fft + nb_pack, 256, 0, stream>>>(
            ft_w, fft_w, stm_idx, nstm_idx, f_stm_idx, f_nstm_idx,
            ws_ft, ws_fft, ws_pidx, n_boards, nb_ft, nb_fft);
    }
    {   // sliced gather: 2 blocks/CU, 32 waves/CU
        int groups = (n_boards + BPB - 1) / BPB;
        nnue_gather<<<groups * NSLICE, 1024, lds_bytes, stream>>>(
            (const unsigned long long*)ws_pidx, (const char*)ws_ft, (const char*)ws_fft,
            ft_b, fft_b, out_w, ws_part, n_boards);
    }
    {   // reduce partials + sigmoid
        nnue_final<<<(n_boards + 255) / 256, 256, 0, stream>>>(ws_part, out_b, out, n_boards);
    }
}

// Round 13
// 132.286 us; speedup vs baseline: 1.3367x; 1.1042x over previous
//
#include <hip/hip_runtime.h>
#include <math.h>

#define FT_IN  40960
#define FFT_IN 640
#define FT_OUT 256
#define NA     30
#define NSLICE 4          // 64-col slices; fp8 rows = 64 B; ft slice 2.62 MB (L2-resident)
#define BPB    128        // boards per gather block (1024 thr = 128 boards x 8 lanes)

typedef float f32x2 __attribute__((ext_vector_type(2)));

__device__ __forceinline__ unsigned enc4(float a, float b, float c, float d) {
    unsigned r = 0;
    r = __builtin_amdgcn_cvt_pk_fp8_f32(a, b, r, false);   // bytes 0,1
    r = __builtin_amdgcn_cvt_pk_fp8_f32(c, d, r, true);    // bytes 2,3
    return r;
}

// ---------- fused prep: f32 -> fp8 e4m3 sliced convert (ft, fft) + index pack ----------
// sliced layout: [NSLICE][nrows][64 fp8]; one row-slice = 64 B = 4 dwords
__device__ __forceinline__ void conv8_block(const float* __restrict__ src,
                                            uint4* __restrict__ dst,
                                            int nrows, int bid, int tid)
{
    int t = bid * 256 + tid;
    int total = nrows * 16;               // 16 x 16-col chunks per 256-col row
    if (t >= total) return;
    int r = t >> 4, g = t & 15;           // chunk g: cols [16g, 16g+16)
    int s = g >> 2, d = g & 3;            // slice (64 cols = 4 chunks), uint4-within-row
    const float4* sp = (const float4*)(src + (size_t)r * FT_OUT + g * 16);
    float4 v0 = sp[0], v1 = sp[1], v2 = sp[2], v3 = sp[3];
    uint4 u;
    u.x = enc4(v0.x, v0.y, v0.z, v0.w);
    u.y = enc4(v1.x, v1.y, v1.z, v1.w);
    u.z = enc4(v2.x, v2.y, v2.z, v2.w);
    u.w = enc4(v3.x, v3.y, v3.z, v3.w);
    dst[((size_t)s * nrows + r) * 4 + d] = u;
}

__global__ __launch_bounds__(256) void prep(
    const float* __restrict__ ft_w, const float* __restrict__ fft_w,
    const int* __restrict__ stm, const int* __restrict__ nstm,
    const int* __restrict__ fstm, const int* __restrict__ fnstm,
    uint4* __restrict__ ft_o, uint4* __restrict__ fft_o,
    ushort4* __restrict__ pidx, int n_boards, int nb_ft, int nb_fft)
{
    int bid = blockIdx.x;
    if (bid < nb_ft) {
        conv8_block(ft_w, ft_o, FT_IN, bid, threadIdx.x);
    } else if (bid < nb_ft + nb_fft) {
        conv8_block(fft_w, fft_o, FFT_IN, bid - nb_ft, threadIdx.x);
    } else {
        int t = (bid - nb_ft - nb_fft) * 256 + (int)threadIdx.x;
        int total = n_boards * NA;
        if (t < total) {
            int board = t / NA, a = t - board * NA;
            ushort4 v;
            v.x = (unsigned short)stm[t];  v.y = (unsigned short)nstm[t];
            v.z = (unsigned short)fstm[t]; v.w = (unsigned short)fnstm[t];
            pidx[(size_t)a * n_boards + board] = v;   // transposed [a][board]
        }
    }
}

// ---------- gather: fp8 everywhere; ft 64 B rows from L2-resident slice;
// fft fp8 in LDS (row-rotated chunks); idx in LDS. 1024 thr = 128 boards x 8
// lanes; LDS 70 KB -> 2 blocks/CU = 32 waves/CU.
__global__ __launch_bounds__(1024, 8) void nnue_gather(
    const uint2* __restrict__ pidx,      // [NA][n_boards] packed ushort4
    const char* __restrict__ ft, const char* __restrict__ fft,
    const float* __restrict__ ft_b, const float* __restrict__ fft_b,
    const float* __restrict__ out_w, float* __restrict__ partial, int n_boards)
{
    extern __shared__ char smem[];
    uint2* lidx = (uint2*)smem;                     // [NA][BPB] = 30720 B
    uint2* lf8  = (uint2*)(smem + NA * BPB * 8);    // [FFT_IN][8 uint2] = 40960 B
    const int slice = blockIdx.x & (NSLICE - 1);
    const int group = blockIdx.x >> 2;
    const int tid = (int)threadIdx.x;

    for (int i = tid; i < NA * BPB; i += 1024) {    // [a][board] rows of 128 uint2
        int b = i & (BPB - 1);
        int bd = group * BPB + b;
        uint2 v; v.x = 0u; v.y = 0u;
        if (bd < n_boards) v = pidx[(size_t)(i >> 7) * n_boards + bd];
        lidx[i] = v;
    }
    {   // stage fft fp8 slice; chunk c of row r stored at (r<<3) + ((c+r)&7)
        const uint2* fsrc = (const uint2*)(fft + (size_t)slice * FFT_IN * 64);
        for (int i = tid; i < FFT_IN * 8; i += 1024) {
            int r = i >> 3, c = i & 7;
            lf8[(r << 3) + ((c + r) & 7)] = fsrc[i];
        }
    }
    __syncthreads();

    const int sub = tid >> 3, ql = tid & 7;
    int board = group * BPB + sub;
    const bool active = board < n_boards;
    const char* ftS = ft + (size_t)slice * FT_IN * 64 + ql * 8;
    const int col = slice * 64 + ql * 8;

    f32x2 a0[4] = {f32x2{0.f,0.f}, f32x2{0.f,0.f}, f32x2{0.f,0.f}, f32x2{0.f,0.f}};
    f32x2 a1[4] = {f32x2{0.f,0.f}, f32x2{0.f,0.f}, f32x2{0.f,0.f}, f32x2{0.f,0.f}};

    #pragma unroll
    for (int a = 0; a < NA; ++a) {
        uint2 iv = lidx[a * BPB + sub];
        uint2 u0 = *(const uint2*)(ftS + ((iv.x & 0xFFFFu) << 6));
        uint2 u1 = *(const uint2*)(ftS + ((iv.x >> 16) << 6));
        unsigned rz = iv.y & 0xFFFFu, rw = iv.y >> 16;
        uint2 g0 = lf8[(rz << 3) + (((unsigned)ql + rz) & 7)];
        uint2 g1 = lf8[(rw << 3) + (((unsigned)ql + rw) & 7)];
        a0[0] += __builtin_amdgcn_cvt_pk_f32_fp8(u0.x, false);
        a0[1] += __builtin_amdgcn_cvt_pk_f32_fp8(u0.x, true);
        a0[2] += __builtin_amdgcn_cvt_pk_f32_fp8(u0.y, false);
        a0[3] += __builtin_amdgcn_cvt_pk_f32_fp8(u0.y, true);
        a1[0] += __builtin_amdgcn_cvt_pk_f32_fp8(u1.x, false);
        a1[1] += __builtin_amdgcn_cvt_pk_f32_fp8(u1.x, true);
        a1[2] += __builtin_amdgcn_cvt_pk_f32_fp8(u1.y, false);
        a1[3] += __builtin_amdgcn_cvt_pk_f32_fp8(u1.y, true);
        a0[0] += __builtin_amdgcn_cvt_pk_f32_fp8(g0.x, false);
        a0[1] += __builtin_amdgcn_cvt_pk_f32_fp8(g0.x, true);
        a0[2] += __builtin_amdgcn_cvt_pk_f32_fp8(g0.y, false);
        a0[3] += __builtin_amdgcn_cvt_pk_f32_fp8(g0.y, true);
        a1[0] += __builtin_amdgcn_cvt_pk_f32_fp8(g1.x, false);
        a1[1] += __builtin_amdgcn_cvt_pk_f32_fp8(g1.x, true);
        a1[2] += __builtin_amdgcn_cvt_pk_f32_fp8(g1.y, false);
        a1[3] += __builtin_amdgcn_cvt_pk_f32_fp8(g1.y, true);
    }

    // epilogue: f32 bias + clip + partial dot
    const float4* bfp = (const float4*)(ft_b  + col);
    const float4* bgp = (const float4*)(fft_b + col);
    float4 bf0 = bfp[0], bf1 = bfp[1], bg0 = bgp[0], bg1 = bgp[1];
    float bias[8] = {bf0.x+bg0.x, bf0.y+bg0.y, bf0.z+bg0.z, bf0.w+bg0.w,
                     bf1.x+bg1.x, bf1.y+bg1.y, bf1.z+bg1.z, bf1.w+bg1.w};
    const float4* w0p = (const float4*)(out_w + col);
    const float4* w1p = (const float4*)(out_w + FT_OUT + col);
    float4 w00 = w0p[0], w01 = w0p[1], w10 = w1p[0], w11 = w1p[1];
    float w0[8] = {w00.x, w00.y, w00.z, w00.w, w01.x, w01.y, w01.z, w01.w};
    float w1[8] = {w10.x, w10.y, w10.z, w10.w, w11.x, w11.y, w11.z, w11.w};
    float h0[8], h1[8];
    #pragma unroll
    for (int i = 0; i < 4; ++i) {
        h0[2*i] = a0[i].x; h0[2*i+1] = a0[i].y;
        h1[2*i] = a1[i].x; h1[2*i+1] = a1[i].y;
    }
    float p = 0.f;
    #pragma unroll
    for (int i = 0; i < 8; ++i) {
        p += fminf(fmaxf(h0[i] + bias[i], 0.f), 1.f) * w0[i];
        p += fminf(fmaxf(h1[i] + bias[i], 0.f), 1.f) * w1[i];
    }
    p += __shfl_xor(p, 1, 64);
    p += __shfl_xor(p, 2, 64);
    p += __shfl_xor(p, 4, 64);
    if (active && ql == 0)
        partial[(size_t)slice * n_boards + board] = p;
}

// ---------- final: sum 4 partials + sigmoid ----------
__global__ __launch_bounds__(256) void nnue_final(
    const float* __restrict__ partial, const float* __restrict__ out_b,
    float* __restrict__ out, int n)
{
    int b = blockIdx.x * blockDim.x + threadIdx.x;
    if (b >= n) return;
    float zv = out_b[0];
    #pragma unroll
    for (int s = 0; s < NSLICE; ++s) zv += partial[(size_t)s * n + b];
    out[b] = 1.0f / (1.0f + expf(-zv));
}

// ---------- fallback: direct f32 gather (if ws too small) ----------
__global__ __launch_bounds__(256) void nnue_fwd_direct(
    const int* __restrict__ stm_idx, const int* __restrict__ nstm_idx,
    const int* __restrict__ f_stm_idx, const int* __restrict__ f_nstm_idx,
    const float* __restrict__ ft_w, const float* __restrict__ ft_b,
    const float* __restrict__ fft_w, const float* __restrict__ fft_b,
    const float* __restrict__ out_w, const float* __restrict__ out_b,
    float* __restrict__ out, int n_boards)
{
    const int board = (int)((blockIdx.x * blockDim.x + threadIdx.x) >> 6);
    const int lane  = (int)(threadIdx.x & 63);
    if (board >= n_boards) return;
    const int col = lane << 2;
    const float4 ftb  = *(const float4*)(ft_b  + col);
    const float4 fftb = *(const float4*)(fft_b + col);
    float a0x = ftb.x + fftb.x, a0y = ftb.y + fftb.y,
          a0z = ftb.z + fftb.z, a0w = ftb.w + fftb.w;
    float a1x = a0x, a1y = a0y, a1z = a0z, a1w = a0w;
    const int* si  = stm_idx    + (size_t)board * NA;
    const int* ni  = nstm_idx   + (size_t)board * NA;
    const int* fsi = f_stm_idx  + (size_t)board * NA;
    const int* fni = f_nstm_idx + (size_t)board * NA;
    #pragma unroll 5
    for (int a = 0; a < NA; ++a) {
        const float4 r0 = *(const float4*)(ft_w  + (size_t)si[a]  * FT_OUT + col);
        const float4 r1 = *(const float4*)(ft_w  + (size_t)ni[a]  * FT_OUT + col);
        const float4 r2 = *(const float4*)(fft_w + (size_t)fsi[a] * FT_OUT + col);
        const float4 r3 = *(const float4*)(fft_w + (size_t)fni[a] * FT_OUT + col);
        a0x += r0.x + r2.x; a0y += r0.y + r2.y; a0z += r0.z + r2.z; a0w += r0.w + r2.w;
        a1x += r1.x + r3.x; a1y += r1.y + r3.y; a1z += r1.z + r3.z; a1w += r1.w + r3.w;
    }
    a0x = fminf(fmaxf(a0x, 0.f), 1.f); a0y = fminf(fmaxf(a0y, 0.f), 1.f);
    a0z = fminf(fmaxf(a0z, 0.f), 1.f); a0w = fminf(fmaxf(a0w, 0.f), 1.f);
    a1x = fminf(fmaxf(a1x, 0.f), 1.f); a1y = fminf(fmaxf(a1y, 0.f), 1.f);
    a1z = fminf(fmaxf(a1z, 0.f), 1.f); a1w = fminf(fmaxf(a1w, 0.f), 1.f);
    const float4 w0 = *(const float4*)(out_w + col);
    const float4 w1 = *(const float4*)(out_w + FT_OUT + col);
    float p = a0x * w0.x + a0y * w0.y + a0z * w0.z + a0w * w0.w
            + a1x * w1.x + a1y * w1.y + a1z * w1.z + a1w * w1.w;
    #pragma unroll
    for (int off = 32; off > 0; off >>= 1) p += __shfl_down(p, off, 64);
    if (lane == 0) out[board] = 1.0f / (1.0f + expf(-(p + out_b[0])));
}

extern "C" void kernel_launch(void* const* d_in, const int* in_sizes, int n_in,
                              void* d_out, int out_size, void* d_ws, size_t ws_size,
                              hipStream_t stream) {
    const int*   stm_idx    = (const int*)d_in[0];
    const int*   nstm_idx   = (const int*)d_in[1];
    const int*   f_stm_idx  = (const int*)d_in[2];
    const int*   f_nstm_idx = (const int*)d_in[3];
    const float* ft_w  = (const float*)d_in[4];
    const float* ft_b  = (const float*)d_in[5];
    const float* fft_w = (const float*)d_in[6];
    const float* fft_b = (const float*)d_in[7];
    const float* out_w = (const float*)d_in[8];
    const float* out_b = (const float*)d_in[9];
    float* out = (float*)d_out;

    const int n_boards = in_sizes[0] / NA;

    const size_t ft_bytes   = (size_t)FT_IN  * FT_OUT;                   // 10.49 MB fp8
    const size_t fft_bytes  = (size_t)FFT_IN * FT_OUT;                   // 160 KB fp8
    const size_t pidx_bytes = (size_t)n_boards * NA * sizeof(ushort4);   // 3.93 MB
    const size_t part_bytes = (size_t)n_boards * NSLICE * sizeof(float); // 256 KB
    const size_t need = ft_bytes + fft_bytes + pidx_bytes + part_bytes;

    const size_t lds_bytes = (size_t)NA * BPB * 8 + (size_t)FFT_IN * 64; // 71680

    bool ok = (ws_size >= need);
    if (ok) {
        ok = (hipFuncSetAttribute((const void*)nnue_gather,
                                  hipFuncAttributeMaxDynamicSharedMemorySize,
                                  (int)lds_bytes) == hipSuccess);
    }
    if (!ok) {
        const int grid = (n_boards + 3) / 4;
        nnue_fwd_direct<<<grid, 256, 0, stream>>>(stm_idx, nstm_idx, f_stm_idx, f_nstm_idx,
                                                  ft_w, ft_b, fft_w, fft_b, out_w, out_b,
                                                  out, n_boards);
        return;
    }

    char* wsp = (char*)d_ws;
    uint4*   ws_ft   = (uint4*)wsp;               wsp += ft_bytes;
    uint4*   ws_fft  = (uint4*)wsp;               wsp += fft_bytes;
    ushort4* ws_pidx = (ushort4*)wsp;             wsp += pidx_bytes;
    float*   ws_part = (float*)wsp;

    {   // fused prep: fp8 converts + index pack in one dispatch
        const int nb_ft   = FT_IN  * 16 / 256;               // 2560
        const int nb_fft  = FFT_IN * 16 / 256;               // 40
        const int nb_pack = (n_boards * NA + 255) / 256;
        prep<<<nb_ft + nb_fft + nb_pack, 256, 0, stream>>>(
            ft_w, fft_w, stm_idx, nstm_idx, f_stm_idx, f_nstm_idx,
            ws_ft, ws_fft, ws_pidx, n_boards, nb_ft, nb_fft);
    }
    {   // sliced gather: 2 blocks/CU, 32 waves/CU
        int groups = (n_boards + BPB - 1) / BPB;
        nnue_gather<<<groups * NSLICE, 1024, lds_bytes, stream>>>(
            (const uint2*)ws_pidx, (const char*)ws_ft, (const char*)ws_fft,
            ft_b, fft_b, out_w, ws_part, n_boards);
    }
    {   // reduce partials + sigmoid
        nnue_final<<<(n_boards + 255) / 256, 256, 0, stream>>>(ws_part, out_b, out, n_boards);
    }
}

// Round 14
// 131.391 us; speedup vs baseline: 1.3459x; 1.0068x over previous
//
#include <hip/hip_runtime.h>
#include <math.h>

#define FT_IN  40960
#define FFT_IN 640
#define FT_OUT 256
#define NA     30
#define NSLICE 4          // 64-col slices; fp8 rows = 64 B; ft slice 2.62 MB (L2-resident)
#define BPB    128        // boards per gather block (1024 thr = 128 boards x 8 lanes)

typedef float f32x2 __attribute__((ext_vector_type(2)));

__device__ __forceinline__ unsigned enc4(float a, float b, float c, float d) {
    unsigned r = 0;
    r = __builtin_amdgcn_cvt_pk_fp8_f32(a, b, r, false);   // bytes 0,1
    r = __builtin_amdgcn_cvt_pk_fp8_f32(c, d, r, true);    // bytes 2,3
    return r;
}

// ---------- fused prep: f32 -> fp8 e4m3 sliced convert (ft, fft) + index pack ----------
// sliced layout: [NSLICE][nrows][64 fp8]; one row-slice = 64 B = 4 dwords
__device__ __forceinline__ void conv8_block(const float* __restrict__ src,
                                            uint4* __restrict__ dst,
                                            int nrows, int bid, int tid)
{
    int t = bid * 256 + tid;
    int total = nrows * 16;               // 16 x 16-col chunks per 256-col row
    if (t >= total) return;
    int r = t >> 4, g = t & 15;           // chunk g: cols [16g, 16g+16)
    int s = g >> 2, d = g & 3;            // slice (64 cols = 4 chunks), uint4-within-row
    const float4* sp = (const float4*)(src + (size_t)r * FT_OUT + g * 16);
    float4 v0 = sp[0], v1 = sp[1], v2 = sp[2], v3 = sp[3];
    uint4 u;
    u.x = enc4(v0.x, v0.y, v0.z, v0.w);
    u.y = enc4(v1.x, v1.y, v1.z, v1.w);
    u.z = enc4(v2.x, v2.y, v2.z, v2.w);
    u.w = enc4(v3.x, v3.y, v3.z, v3.w);
    dst[((size_t)s * nrows + r) * 4 + d] = u;
}

__global__ __launch_bounds__(256) void prep(
    const float* __restrict__ ft_w, const float* __restrict__ fft_w,
    const int* __restrict__ stm, const int* __restrict__ nstm,
    const int* __restrict__ fstm, const int* __restrict__ fnstm,
    uint4* __restrict__ ft_o, uint4* __restrict__ fft_o,
    uint2* __restrict__ pidx, int n_boards, int nb_ft, int nb_fft)
{
    int bid = blockIdx.x;
    if (bid < nb_ft) {
        conv8_block(ft_w, ft_o, FT_IN, bid, threadIdx.x);
    } else if (bid < nb_ft + nb_fft) {
        conv8_block(fft_w, fft_o, FFT_IN, bid - nb_ft, threadIdx.x);
    } else {
        int t = (bid - nb_ft - nb_fft) * 256 + (int)threadIdx.x;
        int total = n_boards * NA;
        if (t < total) {
            // natural [board][a] layout: pure streaming copy, coalesced both ends
            uint2 v;
            v.x = (unsigned)stm[t]  | ((unsigned)nstm[t]  << 16);
            v.y = (unsigned)fstm[t] | ((unsigned)fnstm[t] << 16);
            pidx[t] = v;
        }
    }
}

// ---------- gather: fp8; ft 64 B rows from L2-resident slice; fft fp8 in LDS
// (row-rotated chunks); idx in LDS (natural [board][a] layout, conflict-free
// broadcast reads). 1024 thr = 128 boards x 8 lanes; LDS 70 KB -> 2 blocks/CU
// = 32 waves/CU.
__global__ __launch_bounds__(1024, 8) void nnue_gather(
    const uint2* __restrict__ pidx,      // [n_boards][NA] packed ushort4
    const char* __restrict__ ft, const char* __restrict__ fft,
    const float* __restrict__ ft_b, const float* __restrict__ fft_b,
    const float* __restrict__ out_w, float* __restrict__ partial, int n_boards)
{
    extern __shared__ char smem[];
    uint2* lidx = (uint2*)smem;                     // [BPB][NA] = 30720 B
    uint2* lf8  = (uint2*)(smem + NA * BPB * 8);    // [FFT_IN][8 uint2] = 40960 B
    const int slice = blockIdx.x & (NSLICE - 1);
    const int group = blockIdx.x >> 2;
    const int tid = (int)threadIdx.x;

    {   // stage this group's indices: one contiguous 30 KB block copy
        const uint2* psrc = pidx + (size_t)group * BPB * NA;
        int lim = (n_boards - group * BPB) * NA;    // guard for ragged tail
        if (lim > NA * BPB) lim = NA * BPB;
        for (int i = tid; i < lim; i += 1024)
            lidx[i] = psrc[i];
    }
    {   // stage fft fp8 slice; chunk c of row r stored at (r<<3) + ((c+r)&7)
        const uint2* fsrc = (const uint2*)(fft + (size_t)slice * FFT_IN * 64);
        for (int i = tid; i < FFT_IN * 8; i += 1024) {
            int r = i >> 3, c = i & 7;
            lf8[(r << 3) + ((c + r) & 7)] = fsrc[i];
        }
    }
    __syncthreads();

    const int sub = tid >> 3, ql = tid & 7;
    int board = group * BPB + sub;
    const bool active = board < n_boards;
    const char* ftS = ft + (size_t)slice * FT_IN * 64 + ql * 8;
    const int col = slice * 64 + ql * 8;

    f32x2 a0[4] = {f32x2{0.f,0.f}, f32x2{0.f,0.f}, f32x2{0.f,0.f}, f32x2{0.f,0.f}};
    f32x2 a1[4] = {f32x2{0.f,0.f}, f32x2{0.f,0.f}, f32x2{0.f,0.f}, f32x2{0.f,0.f}};

    const uint2* myidx = lidx + sub * NA;

    #pragma unroll
    for (int a = 0; a < NA; ++a) {
        uint2 iv = myidx[a];
        uint2 u0 = *(const uint2*)(ftS + ((iv.x & 0xFFFFu) << 6));
        uint2 u1 = *(const uint2*)(ftS + ((iv.x >> 16) << 6));
        unsigned rz = iv.y & 0xFFFFu, rw = iv.y >> 16;
        uint2 g0 = lf8[(rz << 3) + (((unsigned)ql + rz) & 7)];
        uint2 g1 = lf8[(rw << 3) + (((unsigned)ql + rw) & 7)];
        a0[0] += __builtin_amdgcn_cvt_pk_f32_fp8(u0.x, false);
        a0[1] += __builtin_amdgcn_cvt_pk_f32_fp8(u0.x, true);
        a0[2] += __builtin_amdgcn_cvt_pk_f32_fp8(u0.y, false);
        a0[3] += __builtin_amdgcn_cvt_pk_f32_fp8(u0.y, true);
        a1[0] += __builtin_amdgcn_cvt_pk_f32_fp8(u1.x, false);
        a1[1] += __builtin_amdgcn_cvt_pk_f32_fp8(u1.x, true);
        a1[2] += __builtin_amdgcn_cvt_pk_f32_fp8(u1.y, false);
        a1[3] += __builtin_amdgcn_cvt_pk_f32_fp8(u1.y, true);
        a0[0] += __builtin_amdgcn_cvt_pk_f32_fp8(g0.x, false);
        a0[1] += __builtin_amdgcn_cvt_pk_f32_fp8(g0.x, true);
        a0[2] += __builtin_amdgcn_cvt_pk_f32_fp8(g0.y, false);
        a0[3] += __builtin_amdgcn_cvt_pk_f32_fp8(g0.y, true);
        a1[0] += __builtin_amdgcn_cvt_pk_f32_fp8(g1.x, false);
        a1[1] += __builtin_amdgcn_cvt_pk_f32_fp8(g1.x, true);
        a1[2] += __builtin_amdgcn_cvt_pk_f32_fp8(g1.y, false);
        a1[3] += __builtin_amdgcn_cvt_pk_f32_fp8(g1.y, true);
    }

    // epilogue: f32 bias + clip + partial dot
    const float4* bfp = (const float4*)(ft_b  + col);
    const float4* bgp = (const float4*)(fft_b + col);
    float4 bf0 = bfp[0], bf1 = bfp[1], bg0 = bgp[0], bg1 = bgp[1];
    float bias[8] = {bf0.x+bg0.x, bf0.y+bg0.y, bf0.z+bg0.z, bf0.w+bg0.w,
                     bf1.x+bg1.x, bf1.y+bg1.y, bf1.z+bg1.z, bf1.w+bg1.w};
    const float4* w0p = (const float4*)(out_w + col);
    const float4* w1p = (const float4*)(out_w + FT_OUT + col);
    float4 w00 = w0p[0], w01 = w0p[1], w10 = w1p[0], w11 = w1p[1];
    float w0[8] = {w00.x, w00.y, w00.z, w00.w, w01.x, w01.y, w01.z, w01.w};
    float w1[8] = {w10.x, w10.y, w10.z, w10.w, w11.x, w11.y, w11.z, w11.w};
    float h0[8], h1[8];
    #pragma unroll
    for (int i = 0; i < 4; ++i) {
        h0[2*i] = a0[i].x; h0[2*i+1] = a0[i].y;
        h1[2*i] = a1[i].x; h1[2*i+1] = a1[i].y;
    }
    float p = 0.f;
    #pragma unroll
    for (int i = 0; i < 8; ++i) {
        p += fminf(fmaxf(h0[i] + bias[i], 0.f), 1.f) * w0[i];
        p += fminf(fmaxf(h1[i] + bias[i], 0.f), 1.f) * w1[i];
    }
    p += __shfl_xor(p, 1, 64);
    p += __shfl_xor(p, 2, 64);
    p += __shfl_xor(p, 4, 64);
    if (active && ql == 0)
        partial[(size_t)slice * n_boards + board] = p;
}

// ---------- final: sum 4 partials + sigmoid ----------
__global__ __launch_bounds__(256) void nnue_final(
    const float* __restrict__ partial, const float* __restrict__ out_b,
    float* __restrict__ out, int n)
{
    int b = blockIdx.x * blockDim.x + threadIdx.x;
    if (b >= n) return;
    float zv = out_b[0];
    #pragma unroll
    for (int s = 0; s < NSLICE; ++s) zv += partial[(size_t)s * n + b];
    out[b] = 1.0f / (1.0f + expf(-zv));
}

// ---------- fallback: direct f32 gather (if ws too small) ----------
__global__ __launch_bounds__(256) void nnue_fwd_direct(
    const int* __restrict__ stm_idx, const int* __restrict__ nstm_idx,
    const int* __restrict__ f_stm_idx, const int* __restrict__ f_nstm_idx,
    const float* __restrict__ ft_w, const float* __restrict__ ft_b,
    const float* __restrict__ fft_w, const float* __restrict__ fft_b,
    const float* __restrict__ out_w, const float* __restrict__ out_b,
    float* __restrict__ out, int n_boards)
{
    const int board = (int)((blockIdx.x * blockDim.x + threadIdx.x) >> 6);
    const int lane  = (int)(threadIdx.x & 63);
    if (board >= n_boards) return;
    const int col = lane << 2;
    const float4 ftb  = *(const float4*)(ft_b  + col);
    const float4 fftb = *(const float4*)(fft_b + col);
    float a0x = ftb.x + fftb.x, a0y = ftb.y + fftb.y,
          a0z = ftb.z + fftb.z, a0w = ftb.w + fftb.w;
    float a1x = a0x, a1y = a0y, a1z = a0z, a1w = a0w;
    const int* si  = stm_idx    + (size_t)board * NA;
    const int* ni  = nstm_idx   + (size_t)board * NA;
    const int* fsi = f_stm_idx  + (size_t)board * NA;
    const int* fni = f_nstm_idx + (size_t)board * NA;
    #pragma unroll 5
    for (int a = 0; a < NA; ++a) {
        const float4 r0 = *(const float4*)(ft_w  + (size_t)si[a]  * FT_OUT + col);
        const float4 r1 = *(const float4*)(ft_w  + (size_t)ni[a]  * FT_OUT + col);
        const float4 r2 = *(const float4*)(fft_w + (size_t)fsi[a] * FT_OUT + col);
        const float4 r3 = *(const float4*)(fft_w + (size_t)fni[a] * FT_OUT + col);
        a0x += r0.x + r2.x; a0y += r0.y + r2.y; a0z += r0.z + r2.z; a0w += r0.w + r2.w;
        a1x += r1.x + r3.x; a1y += r1.y + r3.y; a1z += r1.z + r3.z; a1w += r1.w + r3.w;
    }
    a0x = fminf(fmaxf(a0x, 0.f), 1.f); a0y = fminf(fmaxf(a0y, 0.f), 1.f);
    a0z = fminf(fmaxf(a0z, 0.f), 1.f); a0w = fminf(fmaxf(a0w, 0.f), 1.f);
    a1x = fminf(fmaxf(a1x, 0.f), 1.f); a1y = fminf(fmaxf(a1y, 0.f), 1.f);
    a1z = fminf(fmaxf(a1z, 0.f), 1.f); a1w = fminf(fmaxf(a1w, 0.f), 1.f);
    const float4 w0 = *(const float4*)(out_w + col);
    const float4 w1 = *(const float4*)(out_w + FT_OUT + col);
    float p = a0x * w0.x + a0y * w0.y + a0z * w0.z + a0w * w0.w
            + a1x * w1.x + a1y * w1.y + a1z * w1.z + a1w * w1.w;
    #pragma unroll
    for (int off = 32; off > 0; off >>= 1) p += __shfl_down(p, off, 64);
    if (lane == 0) out[board] = 1.0f / (1.0f + expf(-(p + out_b[0])));
}

extern "C" void kernel_launch(void* const* d_in, const int* in_sizes, int n_in,
                              void* d_out, int out_size, void* d_ws, size_t ws_size,
                              hipStream_t stream) {
    const int*   stm_idx    = (const int*)d_in[0];
    const int*   nstm_idx   = (const int*)d_in[1];
    const int*   f_stm_idx  = (const int*)d_in[2];
    const int*   f_nstm_idx = (const int*)d_in[3];
    const float* ft_w  = (const float*)d_in[4];
    const float* ft_b  = (const float*)d_in[5];
    const float* fft_w = (const float*)d_in[6];
    const float* fft_b = (const float*)d_in[7];
    const float* out_w = (const float*)d_in[8];
    const float* out_b = (const float*)d_in[9];
    float* out = (float*)d_out;

    const int n_boards = in_sizes[0] / NA;

    const size_t ft_bytes   = (size_t)FT_IN  * FT_OUT;                   // 10.49 MB fp8
    const size_t fft_bytes  = (size_t)FFT_IN * FT_OUT;                   // 160 KB fp8
    const size_t pidx_bytes = (size_t)n_boards * NA * sizeof(uint2);     // 3.93 MB
    const size_t part_bytes = (size_t)n_boards * NSLICE * sizeof(float); // 256 KB
    const size_t need = ft_bytes + fft_bytes + pidx_bytes + part_bytes;

    const size_t lds_bytes = (size_t)NA * BPB * 8 + (size_t)FFT_IN * 64; // 71680

    bool ok = (ws_size >= need);
    if (ok) {
        ok = (hipFuncSetAttribute((const void*)nnue_gather,
                                  hipFuncAttributeMaxDynamicSharedMemorySize,
                                  (int)lds_bytes) == hipSuccess);
    }
    if (!ok) {
        const int grid = (n_boards + 3) / 4;
        nnue_fwd_direct<<<grid, 256, 0, stream>>>(stm_idx, nstm_idx, f_stm_idx, f_nstm_idx,
                                                  ft_w, ft_b, fft_w, fft_b, out_w, out_b,
                                                  out, n_boards);
        return;
    }

    char* wsp = (char*)d_ws;
    uint4* ws_ft   = (uint4*)wsp;               wsp += ft_bytes;
    uint4* ws_fft  = (uint4*)wsp;               wsp += fft_bytes;
    uint2* ws_pidx = (uint2*)wsp;               wsp += pidx_bytes;
    float* ws_part = (float*)wsp;

    {   // fused prep: fp8 converts + streaming index pack in one dispatch
        const int nb_ft   = FT_IN  * 16 / 256;               // 2560
        const int nb_fft  = FFT_IN * 16 / 256;               // 40
        const int nb_pack = (n_boards * NA + 255) / 256;
        prep<<<nb_ft + nb_fft + nb_pack, 256, 0, stream>>>(
            ft_w, fft_w, stm_idx, nstm_idx, f_stm_idx, f_nstm_idx,
            ws_ft, ws_fft, ws_pidx, n_boards, nb_ft, nb_fft);
    }
    {   // sliced gather: 2 blocks/CU, 32 waves/CU
        int groups = (n_boards + BPB - 1) / BPB;
        nnue_gather<<<groups * NSLICE, 1024, lds_bytes, stream>>>(
            (const uint2*)ws_pidx, (const char*)ws_ft, (const char*)ws_fft,
            ft_b, fft_b, out_w, ws_part, n_boards);
    }
    {   // reduce partials + sigmoid
        nnue_final<<<(n_boards + 255) / 256, 256, 0, stream>>>(ws_part, out_b, out, n_boards);
    }
}